// Round 3
// baseline (319.179 us; speedup 1.0000x reference)
//
#include <hip/hip_runtime.h>
#include <hip/hip_bf16.h>

#define BATCH 4
#define SEQ   4096
#define DIN   512
#define DOUT  64

typedef __attribute__((ext_vector_type(4))) float f32x4;
typedef __attribute__((ext_vector_type(8))) short bf16x8;   // 8 bf16 = 4 VGPRs
typedef __attribute__((ext_vector_type(4))) short bf16x4;   // 4 bf16 = 2 VGPRs

__device__ __forceinline__ f32x4 mfma16(bf16x8 a, bf16x8 b, f32x4 c) {
    return __builtin_amdgcn_mfma_f32_16x16x32_bf16(a, b, c, 0, 0, 0);
}
// K=16 variant: A[m][k]: m=lane&15, k=quad*4+j ; B[k][n]: n=lane&15, k=quad*4+j
__device__ __forceinline__ f32x4 mfma16k(bf16x4 a, bf16x4 b, f32x4 c) {
    return __builtin_amdgcn_mfma_f32_16x16x16bf16_1k(a, b, c, 0, 0, 0);
}

// fp32 -> bf16 round-to-nearest-even (finite inputs only)
__device__ __forceinline__ short f2bf(float f) {
    union { float f; unsigned u; } x; x.f = f;
    unsigned r = x.u + 0x7FFFu + ((x.u >> 16) & 1u);
    return (short)(r >> 16);
}

// pack two fp32 into bf16x2 (truncation) in ONE v_perm_b32: lo -> low16, hi -> high16
__device__ __forceinline__ unsigned pack_bf2(float lo, float hi) {
    union { float f; unsigned u; } a, b; a.f = lo; b.f = hi;
    return __builtin_amdgcn_perm(b.u, a.u, 0x07060302u);
}

// Q pre-scale: 1/sqrt(64) * log2(e)  (softmax done in base 2)
#define QSCALE 0.1803368801111204f

// ---------------------------------------------------------------------------
// W convert+transpose: W[512][64] fp32 -> Wt[64][512] bf16 (coalesced reads).
// ---------------------------------------------------------------------------
__global__ __launch_bounds__(256) void wconv_kernel(
    const float* __restrict__ Wq, const float* __restrict__ Wk,
    const float* __restrict__ Wv, short* __restrict__ Wt)
{
    const int m = blockIdx.y;
    const float* W = (m == 0) ? Wq : (m == 1) ? Wk : Wv;
    const int idx = blockIdx.x * 256 + threadIdx.x;   // 0..32767
    const int k = idx >> 6;
    const int n = idx & 63;
    Wt[m * (DOUT * DIN) + n * DIN + k] = f2bf(W[idx]);
}

// ---------------------------------------------------------------------------
// QKV projection, bf16 MFMA, software-pipelined loads.
// m<2 : C = X·W  (A=X-frag, B=Wt-frag)  -> Qb/Kb row-major [s][e]
//       (Q additionally scaled by QSCALE)
// m==2: C = Wt·X^T (operands swapped)   -> Vt transposed [e][s], cols = s
//       so stores are 32B-contiguous across l16 lanes.
// Both use IDENTICAL Wt/X loads; only mfma operand order differs.
// ---------------------------------------------------------------------------
__global__ __launch_bounds__(256) void proj_kernel(
    const float* __restrict__ Xq, const float* __restrict__ Xk, const float* __restrict__ Xv,
    const short* __restrict__ Wt,
    short* __restrict__ Qb, short* __restrict__ Kb, short* __restrict__ Vt)
{
    const int m = blockIdx.y;
    const float* X  = (m == 0) ? Xq : (m == 1) ? Xk : Xv;
    const short* Wm = Wt + m * (DOUT * DIN);

    const int tid  = threadIdx.x;
    const int wv   = tid >> 6;
    const int lane = tid & 63;
    const int quad = lane >> 4;
    const int l16  = lane & 15;
    const long row0 = (long)blockIdx.x * 64 + wv * 16;

    f32x4 acc[4];
    #pragma unroll
    for (int e = 0; e < 4; ++e) acc[e] = (f32x4){0.f, 0.f, 0.f, 0.f};

    const float* xp = X + (row0 + l16) * DIN + quad * 8;
    const short* wp = Wm + l16 * DIN + quad * 8;    // e-tile stride = 16*DIN

    // prologue: preload iter 0
    float4 cxa = *(const float4*)(xp);
    float4 cxb = *(const float4*)(xp + 4);
    bf16x8 cw0 = *(const bf16x8*)(wp);
    bf16x8 cw1 = *(const bf16x8*)(wp + 16 * DIN);
    bf16x8 cw2 = *(const bf16x8*)(wp + 32 * DIN);
    bf16x8 cw3 = *(const bf16x8*)(wp + 48 * DIN);

    #pragma unroll 4
    for (int k0 = 0; k0 < DIN; k0 += 32) {
        const int kn = (k0 + 32 < DIN) ? (k0 + 32) : 0;   // last prefetch is dead
        float4 nxa = *(const float4*)(xp + kn);
        float4 nxb = *(const float4*)(xp + kn + 4);
        bf16x8 nw0 = *(const bf16x8*)(wp + kn);
        bf16x8 nw1 = *(const bf16x8*)(wp + kn + 16 * DIN);
        bf16x8 nw2 = *(const bf16x8*)(wp + kn + 32 * DIN);
        bf16x8 nw3 = *(const bf16x8*)(wp + kn + 48 * DIN);

        bf16x8 af;
        af[0] = f2bf(cxa.x); af[1] = f2bf(cxa.y); af[2] = f2bf(cxa.z); af[3] = f2bf(cxa.w);
        af[4] = f2bf(cxb.x); af[5] = f2bf(cxb.y); af[6] = f2bf(cxb.z); af[7] = f2bf(cxb.w);

        if (m < 2) {
            acc[0] = mfma16(af, cw0, acc[0]);
            acc[1] = mfma16(af, cw1, acc[1]);
            acc[2] = mfma16(af, cw2, acc[2]);
            acc[3] = mfma16(af, cw3, acc[3]);
        } else {
            acc[0] = mfma16(cw0, af, acc[0]);
            acc[1] = mfma16(cw1, af, acc[1]);
            acc[2] = mfma16(cw2, af, acc[2]);
            acc[3] = mfma16(cw3, af, acc[3]);
        }
        cxa = nxa; cxb = nxb;
        cw0 = nw0; cw1 = nw1; cw2 = nw2; cw3 = nw3;
    }

    if (m < 2) {
        short* O = (m == 0) ? Qb : Kb;
        const float sc = (m == 0) ? QSCALE : 1.0f;
        #pragma unroll
        for (int e = 0; e < 4; ++e)
            #pragma unroll
            for (int r = 0; r < 4; ++r)
                O[(row0 + quad * 4 + r) * DOUT + e * 16 + l16] = f2bf(acc[e][r] * sc);
    } else {
        const long b = row0 >> 12;
        const long s = row0 & (SEQ - 1);
        #pragma unroll
        for (int e = 0; e < 4; ++e)
            #pragma unroll
            for (int r = 0; r < 4; ++r)
                Vt[(b * DOUT + e * 16 + quad * 4 + r) * SEQ + s + l16] = f2bf(acc[e][r]);
    }
}

// ---------------------------------------------------------------------------
// Causal flash attention, fully transposed domain (scores^T = K·Q^T).
// Block = one 16-row q-tile (heavy-first order), 4 waves KV-split (stride 128).
// Per lane: q = l16 (fixed); keys live in regs (key = quad*4 + r) ->
// softmax reductions are in-register + 2 cross-quad shuffles. PV uses
// 16x16x16 MFMA whose B-layout (k=quad*4+j) EQUALS the score C-layout:
// no cross-lane P movement, no LDS in the loop. O accumulated as O^T.
// K/V prefetched one iteration ahead.
// ---------------------------------------------------------------------------
__global__ __launch_bounds__(256) void flash_kernel(
    const short* __restrict__ Qb, const short* __restrict__ Kb,
    const short* __restrict__ Vt, float* __restrict__ Out)
{
    __shared__ float s_m[4][16];
    __shared__ float s_l[4][16];
    __shared__ float s_acc[4][16][65];

    const int b    = blockIdx.y;
    const int tid  = threadIdx.x;
    const int wv   = tid >> 6;
    const int lane = tid & 63;
    const int quad = lane >> 4;
    const int l16  = lane & 15;
    const int qt   = gridDim.x - 1 - blockIdx.x;   // heavy tiles first
    const int q0   = qt * 16;

    // Q as B-frag: B[k=d][n=q]; register content identical to row-major load
    const short* Qp = Qb + ((long)b * SEQ + q0 + l16) * DOUT + quad * 8;
    bf16x8 qf0 = *(const bf16x8*)(Qp);        // d = 0..31
    bf16x8 qf1 = *(const bf16x8*)(Qp + 32);   // d = 32..63

    const short* Kbase = Kb + (long)b * SEQ * DOUT;
    const short* Vbase = Vt + (long)b * DOUT * SEQ;

    f32x4 acc[4];   // O^T tiles: row=e-offset(quad*4+r), col=q(l16)
    #pragma unroll
    for (int e = 0; e < 4; ++e) acc[e] = (f32x4){0.f, 0.f, 0.f, 0.f};
    float mrow = -1e30f, lrow = 0.f;

    const int q_hi = q0 + 15;
    const int qg   = q0 + l16;

    int s0 = wv * 32;
    if (s0 <= q_hi) {
        // preload iter 0
        const short* kp = Kbase + (long)(s0 + l16) * DOUT + quad * 8;
        bf16x8 ck00 = *(const bf16x8*)(kp);
        bf16x8 ck01 = *(const bf16x8*)(kp + 32);
        bf16x8 ck10 = *(const bf16x8*)(kp + 16 * DOUT);
        bf16x8 ck11 = *(const bf16x8*)(kp + 16 * DOUT + 32);
        bf16x4 cv0[4], cv1[4];
        #pragma unroll
        for (int et = 0; et < 4; ++et) {
            const short* vp = Vbase + (long)(et * 16 + l16) * SEQ + s0 + quad * 4;
            cv0[et] = *(const bf16x4*)(vp);
            cv1[et] = *(const bf16x4*)(vp + 16);
        }

        #pragma unroll 2
        for (; s0 <= q_hi; s0 += 128) {
            // ---- scores^T: 32 keys x 16 q ----
            f32x4 sc0 = (f32x4){0.f, 0.f, 0.f, 0.f};
            f32x4 sc1 = (f32x4){0.f, 0.f, 0.f, 0.f};
            sc0 = mfma16(ck00, qf0, sc0);
            sc0 = mfma16(ck01, qf1, sc0);
            sc1 = mfma16(ck10, qf0, sc1);
            sc1 = mfma16(ck11, qf1, sc1);

            // ---- prefetch next iter (clamped to a valid tile) ----
            const int sn = s0 + 128;
            const int sb = (sn <= q_hi) ? sn : s0;
            const short* kpn = Kbase + (long)(sb + l16) * DOUT + quad * 8;
            bf16x8 nk00 = *(const bf16x8*)(kpn);
            bf16x8 nk01 = *(const bf16x8*)(kpn + 32);
            bf16x8 nk10 = *(const bf16x8*)(kpn + 16 * DOUT);
            bf16x8 nk11 = *(const bf16x8*)(kpn + 16 * DOUT + 32);
            bf16x4 nv0[4], nv1[4];
            #pragma unroll
            for (int et = 0; et < 4; ++et) {
                const short* vpn = Vbase + (long)(et * 16 + l16) * SEQ + sb + quad * 4;
                nv0[et] = *(const bf16x4*)(vpn);
                nv1[et] = *(const bf16x4*)(vpn + 16);
            }

            // ---- causal mask (key <= q); scores already have log2e folded ----
            #pragma unroll
            for (int r = 0; r < 4; ++r) {
                sc0[r] = ((s0 + quad * 4 + r)      <= qg) ? sc0[r] : -1e30f;
                sc1[r] = ((s0 + 16 + quad * 4 + r) <= qg) ? sc1[r] : -1e30f;
            }

            // ---- online softmax (base 2), per-lane q ----
            float tm = fmaxf(fmaxf(fmaxf(sc0[0], sc0[1]), fmaxf(sc0[2], sc0[3])),
                             fmaxf(fmaxf(sc1[0], sc1[1]), fmaxf(sc1[2], sc1[3])));
            tm = fmaxf(tm, __shfl_xor(tm, 16, 64));
            tm = fmaxf(tm, __shfl_xor(tm, 32, 64));
            const float mn = fmaxf(mrow, tm);
            const float alpha = __builtin_amdgcn_exp2f(mrow - mn);
            mrow = mn;
            float p0[4], p1[4];
            #pragma unroll
            for (int r = 0; r < 4; ++r) {
                p0[r] = __builtin_amdgcn_exp2f(sc0[r] - mn);
                p1[r] = __builtin_amdgcn_exp2f(sc1[r] - mn);
            }
            float rs = (p0[0] + p0[1]) + (p0[2] + p0[3])
                     + (p1[0] + p1[1]) + (p1[2] + p1[3]);
            rs += __shfl_xor(rs, 16, 64);
            rs += __shfl_xor(rs, 32, 64);
            lrow = lrow * alpha + rs;
            #pragma unroll
            for (int e = 0; e < 4; ++e)
                #pragma unroll
                for (int r = 0; r < 4; ++r) acc[e][r] *= alpha;

            // ---- pack P (already in B-frag layout for K=16 MFMA) ----
            union { unsigned u[2]; bf16x4 v; } pf0, pf1;
            pf0.u[0] = pack_bf2(p0[0], p0[1]);
            pf0.u[1] = pack_bf2(p0[2], p0[3]);
            pf1.u[0] = pack_bf2(p1[0], p1[1]);
            pf1.u[1] = pack_bf2(p1[2], p1[3]);

            // ---- O^T += V^T · P^T ----
            #pragma unroll
            for (int et = 0; et < 4; ++et) acc[et] = mfma16k(cv0[et], pf0.v, acc[et]);
            #pragma unroll
            for (int et = 0; et < 4; ++et) acc[et] = mfma16k(cv1[et], pf1.v, acc[et]);

            ck00 = nk00; ck01 = nk01; ck10 = nk10; ck11 = nk11;
            #pragma unroll
            for (int et = 0; et < 4; ++et) { cv0[et] = nv0[et]; cv1[et] = nv1[et]; }
        }
    }

    // ---- publish per-wave partials (per lane: one q-row = l16) ----
    if (quad == 0) { s_m[wv][l16] = mrow; s_l[wv][l16] = lrow; }
    #pragma unroll
    for (int et = 0; et < 4; ++et)
        #pragma unroll
        for (int r = 0; r < 4; ++r)
            s_acc[wv][l16][et * 16 + quad * 4 + r] = acc[et][r];
    __syncthreads();

    // ---- merge 4 wave-partials; thread = (row-group, col) ----
    const int col = tid & 63;
    const int r0  = (tid >> 6) * 4;
    float* outp = Out + ((long)b * SEQ + q0) * DOUT;
    #pragma unroll
    for (int r = 0; r < 4; ++r) {
        const int row = r0 + r;
        const float m0 = s_m[0][row], m1 = s_m[1][row];
        const float m2 = s_m[2][row], m3 = s_m[3][row];
        const float mM = fmaxf(fmaxf(m0, m1), fmaxf(m2, m3));
        const float a0 = __builtin_amdgcn_exp2f(m0 - mM);
        const float a1 = __builtin_amdgcn_exp2f(m1 - mM);
        const float a2 = __builtin_amdgcn_exp2f(m2 - mM);
        const float a3 = __builtin_amdgcn_exp2f(m3 - mM);
        const float li = a0 * s_l[0][row] + a1 * s_l[1][row]
                       + a2 * s_l[2][row] + a3 * s_l[3][row];
        const float o  = a0 * s_acc[0][row][col] + a1 * s_acc[1][row][col]
                       + a2 * s_acc[2][row][col] + a3 * s_acc[3][row][col];
        outp[row * DOUT + col] = o / li;
    }
}

extern "C" void kernel_launch(void* const* d_in, const int* in_sizes, int n_in,
                              void* d_out, int out_size, void* d_ws, size_t ws_size,
                              hipStream_t stream) {
    const float* key_in   = (const float*)d_in[0];
    const float* value_in = (const float*)d_in[1];
    const float* query_in = (const float*)d_in[2];
    const float* Wq = (const float*)d_in[3];
    const float* Wk = (const float*)d_in[4];
    const float* Wv = (const float*)d_in[5];
    float* out = (float*)d_out;

    short* Qb = (short*)d_ws;                          // 2 MB bf16 [B][S][64]  (pre-scaled)
    short* Kb = Qb + (long)BATCH * SEQ * DOUT;         // 2 MB bf16 [B][S][64]
    short* Vt = Kb + (long)BATCH * SEQ * DOUT;         // 2 MB bf16 [B][64][S]
    short* Wt = Vt + (long)BATCH * SEQ * DOUT;         // 192 KB bf16 [3][64][512]

    dim3 wgrid((DOUT * DIN) / 256, 3);
    wconv_kernel<<<wgrid, 256, 0, stream>>>(Wq, Wk, Wv, Wt);

    dim3 pgrid(BATCH * SEQ / 64, 3);
    proj_kernel<<<pgrid, 256, 0, stream>>>(query_in, key_in, value_in,
                                           Wt, Qb, Kb, Vt);

    dim3 fgrid(SEQ / 16, BATCH);
    flash_kernel<<<fgrid, 256, 0, stream>>>(Qb, Kb, Vt, out);
}

// Round 4
// 316.598 us; speedup vs baseline: 1.0082x; 1.0082x over previous
//
#include <hip/hip_runtime.h>
#include <hip/hip_bf16.h>

#define BATCH 4
#define SEQ   4096
#define DIN   512
#define DOUT  64

typedef __attribute__((ext_vector_type(4))) float f32x4;
typedef __attribute__((ext_vector_type(8))) short bf16x8;   // 8 bf16 = 4 VGPRs
typedef __attribute__((ext_vector_type(4))) short bf16x4;   // 4 bf16 = 2 VGPRs

__device__ __forceinline__ f32x4 mfma16(bf16x8 a, bf16x8 b, f32x4 c) {
    return __builtin_amdgcn_mfma_f32_16x16x32_bf16(a, b, c, 0, 0, 0);
}
// K=16 variant: A[m][k]: m=lane&15, k=quad*4+j ; B[k][n]: n=lane&15, k=quad*4+j
__device__ __forceinline__ f32x4 mfma16k(bf16x4 a, bf16x4 b, f32x4 c) {
    return __builtin_amdgcn_mfma_f32_16x16x16bf16_1k(a, b, c, 0, 0, 0);
}

// fp32 -> bf16 round-to-nearest-even (finite inputs only)
__device__ __forceinline__ short f2bf(float f) {
    union { float f; unsigned u; } x; x.f = f;
    unsigned r = x.u + 0x7FFFu + ((x.u >> 16) & 1u);
    return (short)(r >> 16);
}

// pack two fp32 into bf16x2 (truncation) in ONE v_perm_b32
__device__ __forceinline__ unsigned pack_bf2(float lo, float hi) {
    union { float f; unsigned u; } a, b; a.f = lo; b.f = hi;
    return __builtin_amdgcn_perm(b.u, a.u, 0x07060302u);
}

// Q pre-scale: 1/sqrt(64) * log2(e)  (softmax done in base 2)
#define QSCALE 0.1803368801111204f

// ---------------------------------------------------------------------------
// W convert+transpose: W[512][64] fp32 -> Wt[64][512] bf16 (coalesced reads).
// ---------------------------------------------------------------------------
__global__ __launch_bounds__(256) void wconv_kernel(
    const float* __restrict__ Wq, const float* __restrict__ Wk,
    const float* __restrict__ Wv, short* __restrict__ Wt)
{
    const int m = blockIdx.y;
    const float* W = (m == 0) ? Wq : (m == 1) ? Wk : Wv;
    const int idx = blockIdx.x * 256 + threadIdx.x;   // 0..32767
    const int k = idx >> 6;
    const int n = idx & 63;
    Wt[m * (DOUT * DIN) + n * DIN + k] = f2bf(W[idx]);
}

// ---------------------------------------------------------------------------
// QKV projection, bf16 MFMA, software-pipelined loads.
// __launch_bounds__(256,2): 256-VGPR cap so the pipeline regs stay live
// (default bound capped at 64 VGPR -> spills -> 135us; see R3 post-mortem).
// m<2 : C = X·W  -> Qb/Kb row-major (Q pre-scaled by QSCALE)
// m==2: C = Wt·X^T (swapped operands) -> Vt[e][s], 32B-contiguous stores.
// ---------------------------------------------------------------------------
__global__ __launch_bounds__(256, 2) void proj_kernel(
    const float* __restrict__ Xq, const float* __restrict__ Xk, const float* __restrict__ Xv,
    const short* __restrict__ Wt,
    short* __restrict__ Qb, short* __restrict__ Kb, short* __restrict__ Vt)
{
    const int m = blockIdx.y;
    const float* X  = (m == 0) ? Xq : (m == 1) ? Xk : Xv;
    const short* Wm = Wt + m * (DOUT * DIN);

    const int tid  = threadIdx.x;
    const int wv   = tid >> 6;
    const int lane = tid & 63;
    const int quad = lane >> 4;
    const int l16  = lane & 15;
    const long row0 = (long)blockIdx.x * 64 + wv * 16;

    f32x4 acc[4];
    #pragma unroll
    for (int e = 0; e < 4; ++e) acc[e] = (f32x4){0.f, 0.f, 0.f, 0.f};

    const float* xp = X + (row0 + l16) * DIN + quad * 8;
    const short* wp = Wm + l16 * DIN + quad * 8;    // e-tile stride = 16*DIN

    // prologue: preload iter 0
    float4 cxa = *(const float4*)(xp);
    float4 cxb = *(const float4*)(xp + 4);
    bf16x8 cw0 = *(const bf16x8*)(wp);
    bf16x8 cw1 = *(const bf16x8*)(wp + 16 * DIN);
    bf16x8 cw2 = *(const bf16x8*)(wp + 32 * DIN);
    bf16x8 cw3 = *(const bf16x8*)(wp + 48 * DIN);

    #pragma unroll 4
    for (int k0 = 0; k0 < DIN; k0 += 32) {
        const int kn = (k0 + 32 < DIN) ? (k0 + 32) : 0;   // last prefetch is dead
        float4 nxa = *(const float4*)(xp + kn);
        float4 nxb = *(const float4*)(xp + kn + 4);
        bf16x8 nw0 = *(const bf16x8*)(wp + kn);
        bf16x8 nw1 = *(const bf16x8*)(wp + kn + 16 * DIN);
        bf16x8 nw2 = *(const bf16x8*)(wp + kn + 32 * DIN);
        bf16x8 nw3 = *(const bf16x8*)(wp + kn + 48 * DIN);

        bf16x8 af;
        af[0] = f2bf(cxa.x); af[1] = f2bf(cxa.y); af[2] = f2bf(cxa.z); af[3] = f2bf(cxa.w);
        af[4] = f2bf(cxb.x); af[5] = f2bf(cxb.y); af[6] = f2bf(cxb.z); af[7] = f2bf(cxb.w);

        if (m < 2) {
            acc[0] = mfma16(af, cw0, acc[0]);
            acc[1] = mfma16(af, cw1, acc[1]);
            acc[2] = mfma16(af, cw2, acc[2]);
            acc[3] = mfma16(af, cw3, acc[3]);
        } else {
            acc[0] = mfma16(cw0, af, acc[0]);
            acc[1] = mfma16(cw1, af, acc[1]);
            acc[2] = mfma16(cw2, af, acc[2]);
            acc[3] = mfma16(cw3, af, acc[3]);
        }
        cxa = nxa; cxb = nxb;
        cw0 = nw0; cw1 = nw1; cw2 = nw2; cw3 = nw3;
    }

    if (m < 2) {
        short* O = (m == 0) ? Qb : Kb;
        const float sc = (m == 0) ? QSCALE : 1.0f;
        #pragma unroll
        for (int e = 0; e < 4; ++e)
            #pragma unroll
            for (int r = 0; r < 4; ++r)
                O[(row0 + quad * 4 + r) * DOUT + e * 16 + l16] = f2bf(acc[e][r] * sc);
    } else {
        const long b = row0 >> 12;
        const long s = row0 & (SEQ - 1);
        #pragma unroll
        for (int e = 0; e < 4; ++e)
            #pragma unroll
            for (int r = 0; r < 4; ++r)
                Vt[(b * DOUT + e * 16 + quad * 4 + r) * SEQ + s + l16] = f2bf(acc[e][r]);
    }
}

// ---------------------------------------------------------------------------
// Causal flash attention, transposed domain (scores^T = K·Q^T), 64 keys/iter.
// __launch_bounds__(256,2): ~220 live VGPRs for 2-stage prefetch of K and V.
// Block = one 16-row q-tile (heavy-first), 4 waves KV-split (stride 256 keys).
// Per lane: q = l16; keys = kh*16 + quad*4 + r. Softmax in-register +
// 4 shuffles per 64 keys. PV via 16x16x16 MFMA: score C-layout == P B-layout,
// no cross-lane P movement. O accumulated as O^T.
// ---------------------------------------------------------------------------
__global__ __launch_bounds__(256, 2) void flash_kernel(
    const short* __restrict__ Qb, const short* __restrict__ Kb,
    const short* __restrict__ Vt, float* __restrict__ Out)
{
    __shared__ float s_m[4][16];
    __shared__ float s_l[4][16];
    __shared__ float s_acc[4][16][65];

    const int b    = blockIdx.y;
    const int tid  = threadIdx.x;
    const int wv   = tid >> 6;
    const int lane = tid & 63;
    const int quad = lane >> 4;
    const int l16  = lane & 15;
    const int qt   = gridDim.x - 1 - blockIdx.x;   // heavy tiles first
    const int q0   = qt * 16;

    // Q as B-frag: B[k=d][n=q]
    const short* Qp = Qb + ((long)b * SEQ + q0 + l16) * DOUT + quad * 8;
    bf16x8 qf0 = *(const bf16x8*)(Qp);        // d = 0..31
    bf16x8 qf1 = *(const bf16x8*)(Qp + 32);   // d = 32..63

    const short* Kbase = Kb + (long)b * SEQ * DOUT;
    const short* Vbase = Vt + (long)b * DOUT * SEQ;

    f32x4 acc[4];   // O^T tiles: row = e-offset (quad*4+r), col = q (l16)
    #pragma unroll
    for (int e = 0; e < 4; ++e) acc[e] = (f32x4){0.f, 0.f, 0.f, 0.f};
    float mrow = -1e30f, lrow = 0.f;

    const int q_hi = q0 + 15;
    const int qg   = q0 + l16;

    // per-lane V row pointers (et = 0..3)
    const short* vrow[4];
    #pragma unroll
    for (int et = 0; et < 4; ++et)
        vrow[et] = Vbase + (long)(et * 16 + l16) * SEQ + quad * 4;

    int s0 = wv * 64;
    if (s0 <= q_hi) {
        // preload iter 0: K frags (8 x 16B), V frags (16 x 8B)
        bf16x8 ck[4][2];
        bf16x4 cv[4][4];
        #pragma unroll
        for (int kh = 0; kh < 4; ++kh) {
            const short* kp = Kbase + (long)(s0 + kh * 16 + l16) * DOUT + quad * 8;
            ck[kh][0] = *(const bf16x8*)(kp);
            ck[kh][1] = *(const bf16x8*)(kp + 32);
        }
        #pragma unroll
        for (int et = 0; et < 4; ++et)
            #pragma unroll
            for (int kh = 0; kh < 4; ++kh)
                cv[et][kh] = *(const bf16x4*)(vrow[et] + s0 + kh * 16);

        for (; s0 <= q_hi; s0 += 256) {
            // ---- scores^T: 64 keys x 16 q ----
            f32x4 sc[4];
            #pragma unroll
            for (int kh = 0; kh < 4; ++kh) {
                sc[kh] = (f32x4){0.f, 0.f, 0.f, 0.f};
                sc[kh] = mfma16(ck[kh][0], qf0, sc[kh]);
                sc[kh] = mfma16(ck[kh][1], qf1, sc[kh]);
            }

            // ---- prefetch next K (clamped to a valid tile) ----
            const int sn = s0 + 256;
            const int sb = (sn <= q_hi) ? sn : s0;
            bf16x8 nk[4][2];
            #pragma unroll
            for (int kh = 0; kh < 4; ++kh) {
                const short* kpn = Kbase + (long)(sb + kh * 16 + l16) * DOUT + quad * 8;
                nk[kh][0] = *(const bf16x8*)(kpn);
                nk[kh][1] = *(const bf16x8*)(kpn + 32);
            }

            // ---- causal mask (key <= q) ----
            #pragma unroll
            for (int kh = 0; kh < 4; ++kh)
                #pragma unroll
                for (int r = 0; r < 4; ++r)
                    sc[kh][r] = ((s0 + kh * 16 + quad * 4 + r) <= qg) ? sc[kh][r] : -1e30f;

            // ---- online softmax (base 2), per-lane q ----
            float tm = -1e30f;
            #pragma unroll
            for (int kh = 0; kh < 4; ++kh)
                #pragma unroll
                for (int r = 0; r < 4; ++r) tm = fmaxf(tm, sc[kh][r]);
            tm = fmaxf(tm, __shfl_xor(tm, 16, 64));
            tm = fmaxf(tm, __shfl_xor(tm, 32, 64));
            const float mn = fmaxf(mrow, tm);
            const float alpha = __builtin_amdgcn_exp2f(mrow - mn);
            mrow = mn;
            float p[4][4];
            float rs = 0.f;
            #pragma unroll
            for (int kh = 0; kh < 4; ++kh)
                #pragma unroll
                for (int r = 0; r < 4; ++r) {
                    p[kh][r] = __builtin_amdgcn_exp2f(sc[kh][r] - mn);
                    rs += p[kh][r];
                }
            rs += __shfl_xor(rs, 16, 64);
            rs += __shfl_xor(rs, 32, 64);
            lrow = lrow * alpha + rs;
            #pragma unroll
            for (int e = 0; e < 4; ++e)
                #pragma unroll
                for (int r = 0; r < 4; ++r) acc[e][r] *= alpha;

            // ---- pack P (already in B-frag layout for K=16 MFMA) ----
            union { unsigned u[2]; bf16x4 v; } pf[4];
            #pragma unroll
            for (int kh = 0; kh < 4; ++kh) {
                pf[kh].u[0] = pack_bf2(p[kh][0], p[kh][1]);
                pf[kh].u[1] = pack_bf2(p[kh][2], p[kh][3]);
            }

            // ---- O^T += V^T · P^T ----
            #pragma unroll
            for (int kh = 0; kh < 4; ++kh)
                #pragma unroll
                for (int et = 0; et < 4; ++et)
                    acc[et] = mfma16k(cv[et][kh], pf[kh].v, acc[et]);

            // ---- prefetch next V (after cv consumed; covers next softmax) ----
            bf16x4 nv[4][4];
            #pragma unroll
            for (int et = 0; et < 4; ++et)
                #pragma unroll
                for (int kh = 0; kh < 4; ++kh)
                    nv[et][kh] = *(const bf16x4*)(vrow[et] + sb + kh * 16);

            #pragma unroll
            for (int kh = 0; kh < 4; ++kh) { ck[kh][0] = nk[kh][0]; ck[kh][1] = nk[kh][1]; }
            #pragma unroll
            for (int et = 0; et < 4; ++et)
                #pragma unroll
                for (int kh = 0; kh < 4; ++kh) cv[et][kh] = nv[et][kh];
        }
    }

    // ---- publish per-wave partials (per lane: one q-row = l16) ----
    if (quad == 0) { s_m[wv][l16] = mrow; s_l[wv][l16] = lrow; }
    #pragma unroll
    for (int et = 0; et < 4; ++et)
        #pragma unroll
        for (int r = 0; r < 4; ++r)
            s_acc[wv][l16][et * 16 + quad * 4 + r] = acc[et][r];
    __syncthreads();

    // ---- merge 4 wave-partials; thread = (row-group, col) ----
    const int col = tid & 63;
    const int r0  = (tid >> 6) * 4;
    float* outp = Out + ((long)b * SEQ + q0) * DOUT;
    #pragma unroll
    for (int r = 0; r < 4; ++r) {
        const int row = r0 + r;
        const float m0 = s_m[0][row], m1 = s_m[1][row];
        const float m2 = s_m[2][row], m3 = s_m[3][row];
        const float mM = fmaxf(fmaxf(m0, m1), fmaxf(m2, m3));
        const float a0 = __builtin_amdgcn_exp2f(m0 - mM);
        const float a1 = __builtin_amdgcn_exp2f(m1 - mM);
        const float a2 = __builtin_amdgcn_exp2f(m2 - mM);
        const float a3 = __builtin_amdgcn_exp2f(m3 - mM);
        const float li = a0 * s_l[0][row] + a1 * s_l[1][row]
                       + a2 * s_l[2][row] + a3 * s_l[3][row];
        const float o  = a0 * s_acc[0][row][col] + a1 * s_acc[1][row][col]
                       + a2 * s_acc[2][row][col] + a3 * s_acc[3][row][col];
        outp[row * DOUT + col] = o / li;
    }
}

extern "C" void kernel_launch(void* const* d_in, const int* in_sizes, int n_in,
                              void* d_out, int out_size, void* d_ws, size_t ws_size,
                              hipStream_t stream) {
    const float* key_in   = (const float*)d_in[0];
    const float* value_in = (const float*)d_in[1];
    const float* query_in = (const float*)d_in[2];
    const float* Wq = (const float*)d_in[3];
    const float* Wk = (const float*)d_in[4];
    const float* Wv = (const float*)d_in[5];
    float* out = (float*)d_out;

    short* Qb = (short*)d_ws;                          // 2 MB bf16 [B][S][64]  (pre-scaled)
    short* Kb = Qb + (long)BATCH * SEQ * DOUT;         // 2 MB bf16 [B][S][64]
    short* Vt = Kb + (long)BATCH * SEQ * DOUT;         // 2 MB bf16 [B][64][S]
    short* Wt = Vt + (long)BATCH * SEQ * DOUT;         // 192 KB bf16 [3][64][512]

    dim3 wgrid((DOUT * DIN) / 256, 3);
    wconv_kernel<<<wgrid, 256, 0, stream>>>(Wq, Wk, Wv, Wt);

    dim3 pgrid(BATCH * SEQ / 64, 3);
    proj_kernel<<<pgrid, 256, 0, stream>>>(query_in, key_in, value_in,
                                           Wt, Qb, Kb, Vt);

    dim3 fgrid(SEQ / 16, BATCH);
    flash_kernel<<<fgrid, 256, 0, stream>>>(Qb, Kb, Vt, out);
}

// Round 5
// 249.143 us; speedup vs baseline: 1.2811x; 1.2707x over previous
//
#include <hip/hip_runtime.h>
#include <hip/hip_bf16.h>

#define BATCH 4
#define SEQ   4096
#define DIN   512
#define DOUT  64

typedef __attribute__((ext_vector_type(4))) float f32x4;
typedef __attribute__((ext_vector_type(8))) short bf16x8;   // 8 bf16 = 4 VGPRs
typedef __attribute__((ext_vector_type(4))) short bf16x4;   // 4 bf16 = 2 VGPRs

__device__ __forceinline__ f32x4 mfma16(bf16x8 a, bf16x8 b, f32x4 c) {
    return __builtin_amdgcn_mfma_f32_16x16x32_bf16(a, b, c, 0, 0, 0);
}
// K=16 variant: A[m][k]: m=lane&15, k=quad*4+j ; B[k][n]: n=lane&15, k=quad*4+j
__device__ __forceinline__ f32x4 mfma16k(bf16x4 a, bf16x4 b, f32x4 c) {
    return __builtin_amdgcn_mfma_f32_16x16x16bf16_1k(a, b, c, 0, 0, 0);
}

// fp32 -> bf16 round-to-nearest-even (finite inputs only)
__device__ __forceinline__ short f2bf(float f) {
    union { float f; unsigned u; } x; x.f = f;
    unsigned r = x.u + 0x7FFFu + ((x.u >> 16) & 1u);
    return (short)(r >> 16);
}

// pack two fp32 into bf16x2 (truncation) in ONE v_perm_b32
__device__ __forceinline__ unsigned pack_bf2(float lo, float hi) {
    union { float f; unsigned u; } a, b; a.f = lo; b.f = hi;
    return __builtin_amdgcn_perm(b.u, a.u, 0x07060302u);
}

// Q pre-scale: 1/sqrt(64) * log2(e)  (softmax done in base 2)
#define QSCALE 0.1803368801111204f

// ---------------------------------------------------------------------------
// W convert+transpose: W[512][64] fp32 -> Wt[64][512] bf16 (coalesced reads).
// ---------------------------------------------------------------------------
__global__ __launch_bounds__(256) void wconv_kernel(
    const float* __restrict__ Wq, const float* __restrict__ Wk,
    const float* __restrict__ Wv, short* __restrict__ Wt)
{
    const int m = blockIdx.y;
    const float* W = (m == 0) ? Wq : (m == 1) ? Wk : Wv;
    const int idx = blockIdx.x * 256 + threadIdx.x;   // 0..32767
    const int k = idx >> 6;
    const int n = idx & 63;
    Wt[m * (DOUT * DIN) + n * DIN + k] = f2bf(W[idx]);
}

// ---------------------------------------------------------------------------
// QKV projection, bf16 MFMA, software-pipelined loads.
// amdgpu_waves_per_eu(2,4): cap the allocator's occupancy TARGET so it keeps
// the ~100 pipeline registers live. R3/R4 evidence: launch_bounds alone lets
// the allocator crush to 48-64 VGPR -> prefetch sunk to uses -> serial
// memory round-trips (135us instead of ~30).
// m<2 : C = X·W  -> Qb/Kb row-major (Q pre-scaled by QSCALE)
// m==2: C = Wt·X^T (swapped operands) -> Vt[e][s], 32B-contiguous stores.
// ---------------------------------------------------------------------------
__global__ __launch_bounds__(256) __attribute__((amdgpu_waves_per_eu(2, 4)))
void proj_kernel(
    const float* __restrict__ Xq, const float* __restrict__ Xk, const float* __restrict__ Xv,
    const short* __restrict__ Wt,
    short* __restrict__ Qb, short* __restrict__ Kb, short* __restrict__ Vt)
{
    const int m = blockIdx.y;
    const float* X  = (m == 0) ? Xq : (m == 1) ? Xk : Xv;
    const short* Wm = Wt + m * (DOUT * DIN);

    const int tid  = threadIdx.x;
    const int wv   = tid >> 6;
    const int lane = tid & 63;
    const int quad = lane >> 4;
    const int l16  = lane & 15;
    const long row0 = (long)blockIdx.x * 64 + wv * 16;

    f32x4 acc[4];
    #pragma unroll
    for (int e = 0; e < 4; ++e) acc[e] = (f32x4){0.f, 0.f, 0.f, 0.f};

    const float* xp = X + (row0 + l16) * DIN + quad * 8;
    const short* wp = Wm + l16 * DIN + quad * 8;    // e-tile stride = 16*DIN

    // prologue: preload iter 0
    float4 cxa = *(const float4*)(xp);
    float4 cxb = *(const float4*)(xp + 4);
    bf16x8 cw0 = *(const bf16x8*)(wp);
    bf16x8 cw1 = *(const bf16x8*)(wp + 16 * DIN);
    bf16x8 cw2 = *(const bf16x8*)(wp + 32 * DIN);
    bf16x8 cw3 = *(const bf16x8*)(wp + 48 * DIN);

    #pragma unroll 4
    for (int k0 = 0; k0 < DIN; k0 += 32) {
        const int kn = (k0 + 32 < DIN) ? (k0 + 32) : 0;   // last prefetch is dead
        float4 nxa = *(const float4*)(xp + kn);
        float4 nxb = *(const float4*)(xp + kn + 4);
        bf16x8 nw0 = *(const bf16x8*)(wp + kn);
        bf16x8 nw1 = *(const bf16x8*)(wp + kn + 16 * DIN);
        bf16x8 nw2 = *(const bf16x8*)(wp + kn + 32 * DIN);
        bf16x8 nw3 = *(const bf16x8*)(wp + kn + 48 * DIN);

        bf16x8 af;
        af[0] = f2bf(cxa.x); af[1] = f2bf(cxa.y); af[2] = f2bf(cxa.z); af[3] = f2bf(cxa.w);
        af[4] = f2bf(cxb.x); af[5] = f2bf(cxb.y); af[6] = f2bf(cxb.z); af[7] = f2bf(cxb.w);

        if (m < 2) {
            acc[0] = mfma16(af, cw0, acc[0]);
            acc[1] = mfma16(af, cw1, acc[1]);
            acc[2] = mfma16(af, cw2, acc[2]);
            acc[3] = mfma16(af, cw3, acc[3]);
        } else {
            acc[0] = mfma16(cw0, af, acc[0]);
            acc[1] = mfma16(cw1, af, acc[1]);
            acc[2] = mfma16(cw2, af, acc[2]);
            acc[3] = mfma16(cw3, af, acc[3]);
        }
        cxa = nxa; cxb = nxb;
        cw0 = nw0; cw1 = nw1; cw2 = nw2; cw3 = nw3;
    }

    if (m < 2) {
        short* O = (m == 0) ? Qb : Kb;
        const float sc = (m == 0) ? QSCALE : 1.0f;
        #pragma unroll
        for (int e = 0; e < 4; ++e)
            #pragma unroll
            for (int r = 0; r < 4; ++r)
                O[(row0 + quad * 4 + r) * DOUT + e * 16 + l16] = f2bf(acc[e][r] * sc);
    } else {
        const long b = row0 >> 12;
        const long s = row0 & (SEQ - 1);
        #pragma unroll
        for (int e = 0; e < 4; ++e)
            #pragma unroll
            for (int r = 0; r < 4; ++r)
                Vt[(b * DOUT + e * 16 + quad * 4 + r) * SEQ + s + l16] = f2bf(acc[e][r]);
    }
}

// ---------------------------------------------------------------------------
// Causal flash attention, transposed domain (scores^T = K·Q^T), 64 keys/iter.
// amdgpu_waves_per_eu(2,3): allocator targets <=3 waves/EU (>=170 VGPR
// budget) so the 2-stage K/V prefetch (~150 live VGPRs) stays in registers.
// 1D grid with XCD swizzle: batch b pinned to XCDs {2b,2b+1} so each XCD's
// 4MiB L2 holds one batch's 2MB KV; heavy q-tiles dispatched first.
// Per lane: q = l16; keys = kh*16 + quad*4 + r. Softmax in-register +
// 4 shuffles per 64 keys. PV via 16x16x16 MFMA: score C-layout == P B-layout,
// no cross-lane P movement. O accumulated as O^T.
// ---------------------------------------------------------------------------
__global__ __launch_bounds__(256) __attribute__((amdgpu_waves_per_eu(2, 3)))
void flash_kernel(
    const short* __restrict__ Qb, const short* __restrict__ Kb,
    const short* __restrict__ Vt, float* __restrict__ Out)
{
    __shared__ float s_m[4][16];
    __shared__ float s_l[4][16];
    __shared__ float s_acc[4][16][65];

    const int i    = blockIdx.x;
    const int b    = (i & 7) >> 1;                       // batch -> XCD pair
    const int qt   = 255 - (((i >> 3) << 1) | (i & 1));  // heavy tiles first
    const int tid  = threadIdx.x;
    const int wv   = tid >> 6;
    const int lane = tid & 63;
    const int quad = lane >> 4;
    const int l16  = lane & 15;
    const int q0   = qt * 16;

    // Q as B-frag: B[k=d][n=q]
    const short* Qp = Qb + ((long)b * SEQ + q0 + l16) * DOUT + quad * 8;
    bf16x8 qf0 = *(const bf16x8*)(Qp);        // d = 0..31
    bf16x8 qf1 = *(const bf16x8*)(Qp + 32);   // d = 32..63

    const short* Kbase = Kb + (long)b * SEQ * DOUT;
    const short* Vbase = Vt + (long)b * DOUT * SEQ;

    f32x4 acc[4];   // O^T tiles: row = e-offset (quad*4+r), col = q (l16)
    #pragma unroll
    for (int e = 0; e < 4; ++e) acc[e] = (f32x4){0.f, 0.f, 0.f, 0.f};
    float mrow = -1e30f, lrow = 0.f;

    const int q_hi = q0 + 15;
    const int qg   = q0 + l16;

    // per-lane V row pointers (et = 0..3)
    const short* vrow[4];
    #pragma unroll
    for (int et = 0; et < 4; ++et)
        vrow[et] = Vbase + (long)(et * 16 + l16) * SEQ + quad * 4;

    int s0 = wv * 64;
    if (s0 <= q_hi) {
        // preload iter 0: K frags (8 x 16B), V frags (16 x 8B)
        bf16x8 ck[4][2];
        bf16x4 cv[4][4];
        #pragma unroll
        for (int kh = 0; kh < 4; ++kh) {
            const short* kp = Kbase + (long)(s0 + kh * 16 + l16) * DOUT + quad * 8;
            ck[kh][0] = *(const bf16x8*)(kp);
            ck[kh][1] = *(const bf16x8*)(kp + 32);
        }
        #pragma unroll
        for (int et = 0; et < 4; ++et)
            #pragma unroll
            for (int kh = 0; kh < 4; ++kh)
                cv[et][kh] = *(const bf16x4*)(vrow[et] + s0 + kh * 16);

        for (; s0 <= q_hi; s0 += 256) {
            // ---- scores^T: 64 keys x 16 q ----
            f32x4 sc[4];
            #pragma unroll
            for (int kh = 0; kh < 4; ++kh) {
                sc[kh] = (f32x4){0.f, 0.f, 0.f, 0.f};
                sc[kh] = mfma16(ck[kh][0], qf0, sc[kh]);
                sc[kh] = mfma16(ck[kh][1], qf1, sc[kh]);
            }

            // ---- prefetch next K (clamped to a valid tile) ----
            const int sn = s0 + 256;
            const int sb = (sn <= q_hi) ? sn : s0;
            bf16x8 nk[4][2];
            #pragma unroll
            for (int kh = 0; kh < 4; ++kh) {
                const short* kpn = Kbase + (long)(sb + kh * 16 + l16) * DOUT + quad * 8;
                nk[kh][0] = *(const bf16x8*)(kpn);
                nk[kh][1] = *(const bf16x8*)(kpn + 32);
            }

            // ---- causal mask (key <= q) ----
            #pragma unroll
            for (int kh = 0; kh < 4; ++kh)
                #pragma unroll
                for (int r = 0; r < 4; ++r)
                    sc[kh][r] = ((s0 + kh * 16 + quad * 4 + r) <= qg) ? sc[kh][r] : -1e30f;

            // ---- online softmax (base 2), per-lane q ----
            float tm = -1e30f;
            #pragma unroll
            for (int kh = 0; kh < 4; ++kh)
                #pragma unroll
                for (int r = 0; r < 4; ++r) tm = fmaxf(tm, sc[kh][r]);
            tm = fmaxf(tm, __shfl_xor(tm, 16, 64));
            tm = fmaxf(tm, __shfl_xor(tm, 32, 64));
            const float mn = fmaxf(mrow, tm);
            const float alpha = __builtin_amdgcn_exp2f(mrow - mn);
            mrow = mn;
            float p[4][4];
            float rs = 0.f;
            #pragma unroll
            for (int kh = 0; kh < 4; ++kh)
                #pragma unroll
                for (int r = 0; r < 4; ++r) {
                    p[kh][r] = __builtin_amdgcn_exp2f(sc[kh][r] - mn);
                    rs += p[kh][r];
                }
            rs += __shfl_xor(rs, 16, 64);
            rs += __shfl_xor(rs, 32, 64);
            lrow = lrow * alpha + rs;
            #pragma unroll
            for (int e = 0; e < 4; ++e)
                #pragma unroll
                for (int r = 0; r < 4; ++r) acc[e][r] *= alpha;

            // ---- pack P (already in B-frag layout for K=16 MFMA) ----
            union { unsigned u[2]; bf16x4 v; } pf[4];
            #pragma unroll
            for (int kh = 0; kh < 4; ++kh) {
                pf[kh].u[0] = pack_bf2(p[kh][0], p[kh][1]);
                pf[kh].u[1] = pack_bf2(p[kh][2], p[kh][3]);
            }

            // ---- O^T += V^T · P^T ----
            #pragma unroll
            for (int kh = 0; kh < 4; ++kh)
                #pragma unroll
                for (int et = 0; et < 4; ++et)
                    acc[et] = mfma16k(cv[et][kh], pf[kh].v, acc[et]);

            // ---- prefetch next V (after cv consumed; covers next softmax) ----
            bf16x4 nv[4][4];
            #pragma unroll
            for (int et = 0; et < 4; ++et)
                #pragma unroll
                for (int kh = 0; kh < 4; ++kh)
                    nv[et][kh] = *(const bf16x4*)(vrow[et] + sb + kh * 16);

            #pragma unroll
            for (int kh = 0; kh < 4; ++kh) { ck[kh][0] = nk[kh][0]; ck[kh][1] = nk[kh][1]; }
            #pragma unroll
            for (int et = 0; et < 4; ++et)
                #pragma unroll
                for (int kh = 0; kh < 4; ++kh) cv[et][kh] = nv[et][kh];
        }
    }

    // ---- publish per-wave partials (per lane: one q-row = l16) ----
    if (quad == 0) { s_m[wv][l16] = mrow; s_l[wv][l16] = lrow; }
    #pragma unroll
    for (int et = 0; et < 4; ++et)
        #pragma unroll
        for (int r = 0; r < 4; ++r)
            s_acc[wv][l16][et * 16 + quad * 4 + r] = acc[et][r];
    __syncthreads();

    // ---- merge 4 wave-partials; thread = (row-group, col) ----
    const int col = tid & 63;
    const int r0  = (tid >> 6) * 4;
    float* outp = Out + ((long)b * SEQ + q0) * DOUT;
    #pragma unroll
    for (int r = 0; r < 4; ++r) {
        const int row = r0 + r;
        const float m0 = s_m[0][row], m1 = s_m[1][row];
        const float m2 = s_m[2][row], m3 = s_m[3][row];
        const float mM = fmaxf(fmaxf(m0, m1), fmaxf(m2, m3));
        const float a0 = __builtin_amdgcn_exp2f(m0 - mM);
        const float a1 = __builtin_amdgcn_exp2f(m1 - mM);
        const float a2 = __builtin_amdgcn_exp2f(m2 - mM);
        const float a3 = __builtin_amdgcn_exp2f(m3 - mM);
        const float li = a0 * s_l[0][row] + a1 * s_l[1][row]
                       + a2 * s_l[2][row] + a3 * s_l[3][row];
        const float o  = a0 * s_acc[0][row][col] + a1 * s_acc[1][row][col]
                       + a2 * s_acc[2][row][col] + a3 * s_acc[3][row][col];
        outp[row * DOUT + col] = o / li;
    }
}

extern "C" void kernel_launch(void* const* d_in, const int* in_sizes, int n_in,
                              void* d_out, int out_size, void* d_ws, size_t ws_size,
                              hipStream_t stream) {
    const float* key_in   = (const float*)d_in[0];
    const float* value_in = (const float*)d_in[1];
    const float* query_in = (const float*)d_in[2];
    const float* Wq = (const float*)d_in[3];
    const float* Wk = (const float*)d_in[4];
    const float* Wv = (const float*)d_in[5];
    float* out = (float*)d_out;

    short* Qb = (short*)d_ws;                          // 2 MB bf16 [B][S][64]  (pre-scaled)
    short* Kb = Qb + (long)BATCH * SEQ * DOUT;         // 2 MB bf16 [B][S][64]
    short* Vt = Kb + (long)BATCH * SEQ * DOUT;         // 2 MB bf16 [B][64][S]
    short* Wt = Vt + (long)BATCH * SEQ * DOUT;         // 192 KB bf16 [3][64][512]

    dim3 wgrid((DOUT * DIN) / 256, 3);
    wconv_kernel<<<wgrid, 256, 0, stream>>>(Wq, Wk, Wv, Wt);

    dim3 pgrid(BATCH * SEQ / 64, 3);
    proj_kernel<<<pgrid, 256, 0, stream>>>(query_in, key_in, value_in,
                                           Wt, Qb, Kb, Vt);

    flash_kernel<<<dim3(SEQ / 16 * BATCH), 256, 0, stream>>>(Qb, Kb, Vt, out);
}